// Round 1
// baseline (554.104 us; speedup 1.0000x reference)
//
#include <hip/hip_runtime.h>
#include <stdint.h>
#include <stddef.h>

// ---------- types ----------
typedef _Float16 f16_t;
typedef _Float16 f16x8 __attribute__((ext_vector_type(8)));
typedef _Float16 f16x4 __attribute__((ext_vector_type(4)));
typedef float    f32x4 __attribute__((ext_vector_type(4)));

#define AS_G __attribute__((address_space(1)))
#define AS_L __attribute__((address_space(3)))

__device__ __forceinline__ void gload_lds16(const void* g, void* l) {
  // async global->LDS, 16B per lane; HW writes lds_base + lane*16
  __builtin_amdgcn_global_load_lds((const AS_G uint32_t*)g, (AS_L uint32_t*)l, 16, 0, 0);
}

#define LN_EPS 1e-12f
#define MASK_NEG -60000.0f  // f16-representable stand-in for -1e9 (exp -> 0)

// ---------- cast fp32 -> f16 (vectorized x4) ----------
__global__ __launch_bounds__(256) void cast_f16_kernel(const float* __restrict__ in,
                                                       f16_t* __restrict__ out) {
  int i = blockIdx.x * 256 + threadIdx.x;
  float4 v = ((const float4*)in)[i];
  f16x4 o = {(f16_t)v.x, (f16_t)v.y, (f16_t)v.z, (f16_t)v.w};
  ((f16x4*)out)[i] = o;
}

// ---------- tiled transpose + cast: in [b][R][C] f32 -> out [b][C][R] f16 ----------
__global__ __launch_bounds__(256) void transpose_f16_kernel(const float* __restrict__ in,
                                                            f16_t* __restrict__ out,
                                                            int R, int C) {
  __shared__ float tile[32][33];
  int b = blockIdx.z;
  const float* inb = in + (size_t)b * R * C;
  f16_t* outb = out + (size_t)b * R * C;
  int tx = threadIdx.x, ty = threadIdx.y;  // 32 x 8
  int c0 = blockIdx.x * 32, r0 = blockIdx.y * 32;
#pragma unroll
  for (int i = 0; i < 32; i += 8)
    tile[ty + i][tx] = inb[(size_t)(r0 + ty + i) * C + (c0 + tx)];
  __syncthreads();
#pragma unroll
  for (int i = 0; i < 32; i += 8)
    outb[(size_t)(c0 + ty + i) * R + (r0 + tx)] = (f16_t)tile[tx][ty + i];
}

// ---------- 128x128 MFMA GEMM, C = A[MxK] * Bt[NxK]^T, f16 in, f16 out ----------
// mode 0: +bias[col]            (Q/K projection)
// mode 1: *scale, mask[col]==0 -> MASK_NEG   (scores)
// mode 2: plain                 (P @ V context)
__global__ __launch_bounds__(256) void gemm_bt_kernel(
    const f16_t* __restrict__ A, const f16_t* __restrict__ Bt, f16_t* __restrict__ C,
    const float* __restrict__ bias, const int* __restrict__ mask,
    int N, int K, float scale, int mode,
    size_t sA, size_t sB, size_t sC, size_t sMask) {
  __shared__ f16_t As[128 * 32];
  __shared__ f16_t Bs[128 * 32];

  const int tid = threadIdx.x;
  const int lane = tid & 63;
  const int wv = tid >> 6;          // wave 0..3
  const int m16 = lane & 15;
  const int quad = lane >> 4;
  const int wr = (wv >> 1) * 64;    // wave row offset in tile
  const int wc = (wv & 1) * 64;     // wave col offset in tile

  const f16_t* Ab = A + (size_t)blockIdx.z * sA + (size_t)blockIdx.x * 128 * K;
  const f16_t* Bb = Bt + (size_t)blockIdx.z * sB + (size_t)blockIdx.y * 128 * K;

  // staging: tile 128x32 f16 = 8KB = 8 wave-calls of 1KB; 2 calls/wave per matrix
  const int lr = lane >> 2;         // 0..15
  const int lc = (lane & 3) * 8;    // 0,8,16,24
  const f16_t* gA0 = Ab + (size_t)(wv * 32 + lr) * K + lc;
  const f16_t* gA1 = Ab + (size_t)(wv * 32 + 16 + lr) * K + lc;
  const f16_t* gB0 = Bb + (size_t)(wv * 32 + lr) * K + lc;
  const f16_t* gB1 = Bb + (size_t)(wv * 32 + 16 + lr) * K + lc;
  f16_t* lA0 = &As[wv * 1024];
  f16_t* lA1 = &As[wv * 1024 + 512];
  f16_t* lB0 = &Bs[wv * 1024];
  f16_t* lB1 = &Bs[wv * 1024 + 512];

  f32x4 acc[4][4] = {};

  for (int k0 = 0; k0 < K; k0 += 32) {
    gload_lds16(gA0 + k0, lA0);
    gload_lds16(gA1 + k0, lA1);
    gload_lds16(gB0 + k0, lB0);
    gload_lds16(gB1 + k0, lB1);
    __syncthreads();  // drains vmcnt, publishes LDS

    f16x8 af[4], bfr[4];
#pragma unroll
    for (int t = 0; t < 4; ++t) {
      af[t] = *(const f16x8*)&As[(wr + t * 16 + m16) * 32 + quad * 8];
      bfr[t] = *(const f16x8*)&Bs[(wc + t * 16 + m16) * 32 + quad * 8];
    }
#pragma unroll
    for (int rt = 0; rt < 4; ++rt)
#pragma unroll
      for (int ct = 0; ct < 4; ++ct)
        acc[rt][ct] = __builtin_amdgcn_mfma_f32_16x16x32_f16(af[rt], bfr[ct], acc[rt][ct], 0, 0, 0);
    __syncthreads();
  }

  // epilogue; C/D layout: col = lane&15, row = quad*4 + reg  [m89-verified]
  f16_t* Cb = C + (size_t)blockIdx.z * sC;
  const int row0 = blockIdx.x * 128 + wr + quad * 4;
  const int col0 = blockIdx.y * 128 + wc + m16;
  if (mode == 0) {
#pragma unroll
    for (int ct = 0; ct < 4; ++ct) {
      int col = col0 + ct * 16;
      float bv = bias[col];
#pragma unroll
      for (int rt = 0; rt < 4; ++rt)
#pragma unroll
        for (int r = 0; r < 4; ++r)
          Cb[(size_t)(row0 + rt * 16 + r) * N + col] = (f16_t)(acc[rt][ct][r] + bv);
    }
  } else if (mode == 1) {
    const int* mp = mask + (size_t)blockIdx.z * sMask;
#pragma unroll
    for (int ct = 0; ct < 4; ++ct) {
      int col = col0 + ct * 16;
      bool keep = (mp[col] != 0);
#pragma unroll
      for (int rt = 0; rt < 4; ++rt)
#pragma unroll
        for (int r = 0; r < 4; ++r) {
          float v = keep ? acc[rt][ct][r] * scale : MASK_NEG;
          Cb[(size_t)(row0 + rt * 16 + r) * N + col] = (f16_t)v;
        }
    }
  } else {
#pragma unroll
    for (int ct = 0; ct < 4; ++ct) {
      int col = col0 + ct * 16;
#pragma unroll
      for (int rt = 0; rt < 4; ++rt)
#pragma unroll
        for (int r = 0; r < 4; ++r)
          Cb[(size_t)(row0 + rt * 16 + r) * N + col] = (f16_t)acc[rt][ct][r];
    }
  }
}

// ---------- row softmax in place: probs [16384][2048] f16 ----------
__global__ __launch_bounds__(256) void softmax_kernel(f16_t* probs) {
  __shared__ float redm[4], reds[4];
  const int tid = threadIdx.x;
  f16_t* p = probs + (size_t)blockIdx.x * 2048;
  f16x8 v8 = ((const f16x8*)p)[tid];
  float v[8];
#pragma unroll
  for (int j = 0; j < 8; ++j) v[j] = (float)v8[j];
  float mx = v[0];
#pragma unroll
  for (int j = 1; j < 8; ++j) mx = fmaxf(mx, v[j]);
#pragma unroll
  for (int off = 32; off > 0; off >>= 1) mx = fmaxf(mx, __shfl_xor(mx, off, 64));
  if ((tid & 63) == 0) redm[tid >> 6] = mx;
  __syncthreads();
  mx = fmaxf(fmaxf(redm[0], redm[1]), fmaxf(redm[2], redm[3]));
  float e[8], s = 0.f;
#pragma unroll
  for (int j = 0; j < 8; ++j) { e[j] = __expf(v[j] - mx); s += e[j]; }
#pragma unroll
  for (int off = 32; off > 0; off >>= 1) s += __shfl_xor(s, off, 64);
  if ((tid & 63) == 0) reds[tid >> 6] = s;
  __syncthreads();
  s = reds[0] + reds[1] + reds[2] + reds[3];
  float inv = 1.0f / s;
  f16x8 o;
#pragma unroll
  for (int j = 0; j < 8; ++j) o[j] = (f16_t)(e[j] * inv);
  ((f16x8*)p)[tid] = o;
}

// ---------- residual + LayerNorm: out[row] = LN(X[row] + Ctx[row]) ----------
__global__ __launch_bounds__(256) void ln_kernel(const float* __restrict__ X,
                                                 const f16_t* __restrict__ Ctx,
                                                 const float* __restrict__ gamma,
                                                 const float* __restrict__ beta,
                                                 float* __restrict__ out) {
  __shared__ float r1[4], r2[4];
  const int tid = threadIdx.x;
  const size_t base = (size_t)blockIdx.x * 1024;
  float4 xv = ((const float4*)(X + base))[tid];
  f16x4 cv = ((const f16x4*)(Ctx + base))[tid];
  float v0 = xv.x + (float)cv[0];
  float v1 = xv.y + (float)cv[1];
  float v2 = xv.z + (float)cv[2];
  float v3 = xv.w + (float)cv[3];
  float s1 = v0 + v1 + v2 + v3;
  float s2 = v0 * v0 + v1 * v1 + v2 * v2 + v3 * v3;
#pragma unroll
  for (int off = 32; off > 0; off >>= 1) {
    s1 += __shfl_xor(s1, off, 64);
    s2 += __shfl_xor(s2, off, 64);
  }
  if ((tid & 63) == 0) { r1[tid >> 6] = s1; r2[tid >> 6] = s2; }
  __syncthreads();
  s1 = r1[0] + r1[1] + r1[2] + r1[3];
  s2 = r2[0] + r2[1] + r2[2] + r2[3];
  float mu = s1 * (1.0f / 1024.0f);
  float var = s2 * (1.0f / 1024.0f) - mu * mu;
  float rs = rsqrtf(fmaxf(var, 0.0f) + LN_EPS);
  float4 gv = ((const float4*)gamma)[tid];
  float4 bv = ((const float4*)beta)[tid];
  float4 o;
  o.x = (v0 - mu) * rs * gv.x + bv.x;
  o.y = (v1 - mu) * rs * gv.y + bv.y;
  o.z = (v2 - mu) * rs * gv.z + bv.z;
  o.w = (v3 - mu) * rs * gv.w + bv.w;
  ((float4*)(out + base))[tid] = o;
}

// ---------- launch ----------
extern "C" void kernel_launch(void* const* d_in, const int* in_sizes, int n_in,
                              void* d_out, int out_size, void* d_ws, size_t ws_size,
                              hipStream_t stream) {
  const float* X     = (const float*)d_in[0];  // [8,2048,1024]
  const int*   masks = (const int*)d_in[1];    // [8,2048]
  const float* Wq    = (const float*)d_in[2];  // [1024,1024]
  const float* bq    = (const float*)d_in[3];
  const float* Wk    = (const float*)d_in[4];
  const float* bk    = (const float*)d_in[5];
  const float* gamma = (const float*)d_in[6];
  const float* beta  = (const float*)d_in[7];
  float* out = (float*)d_out;

  // workspace layout (bytes); Ctx aliases Xb (Xb dead after K-projection)
  if (ws_size < 138412032u) return;  // need 132 MiB
  char* ws = (char*)d_ws;
  f16_t* Xb  = (f16_t*)(ws + 0);          // [16384][1024] f16 (also Ctx later)
  f16_t* Xt  = (f16_t*)(ws + 33554432);   // [8][1024][2048] f16  (X^T per batch)
  f16_t* Wqt = (f16_t*)(ws + 67108864);   // [1024][1024] f16 (Wq^T)
  f16_t* Wkt = (f16_t*)(ws + 69206016);   // [1024][1024] f16 (Wk^T)
  f16_t* Qb  = (f16_t*)(ws + 71303168);   // [16384][1024] f16
  f16_t* Kb  = (f16_t*)(ws + 104857600);  // [16384][1024] f16
  f16_t* Ctx = Xb;
  f16_t* probs = (f16_t*)d_out;           // [8][2048][2048] f16 == 64 MiB == d_out

  const size_t SH = 2048u * 1024u;        // per-batch stride of [S,H]
  const size_t SS = 2048u * 2048u;        // per-batch stride of [S,S]
  const size_t HS = 1024u * 2048u;        // per-batch stride of [H,S]

  // 1. casts / transposes
  cast_f16_kernel<<<16384, 256, 0, stream>>>(X, Xb);
  transpose_f16_kernel<<<dim3(32, 64, 8), dim3(32, 8), 0, stream>>>(X, Xt, 2048, 1024);
  transpose_f16_kernel<<<dim3(32, 32, 1), dim3(32, 8), 0, stream>>>(Wq, Wqt, 1024, 1024);
  transpose_f16_kernel<<<dim3(32, 32, 1), dim3(32, 8), 0, stream>>>(Wk, Wkt, 1024, 1024);

  // 2. Q = X*Wq + bq ; K = X*Wk + bk   (M=16384, N=1024, K=1024)
  gemm_bt_kernel<<<dim3(128, 8, 1), 256, 0, stream>>>(
      Xb, Wqt, Qb, bq, nullptr, 1024, 1024, 0.f, 0, 0, 0, 0, 0);
  gemm_bt_kernel<<<dim3(128, 8, 1), 256, 0, stream>>>(
      Xb, Wkt, Kb, bk, nullptr, 1024, 1024, 0.f, 0, 0, 0, 0, 0);

  // 3. scores = Q K^T / 32, masked   (per batch: M=2048, N=2048, K=1024)
  gemm_bt_kernel<<<dim3(16, 16, 8), 256, 0, stream>>>(
      Qb, Kb, probs, nullptr, masks, 2048, 1024, 0.03125f, 1, SH, SH, SS, 2048);

  // 4. softmax rows in place
  softmax_kernel<<<16384, 256, 0, stream>>>(probs);

  // 5. context = P @ X   (per batch: M=2048, N=1024, K=2048; Bt = X^T)
  gemm_bt_kernel<<<dim3(16, 8, 8), 256, 0, stream>>>(
      probs, Xt, Ctx, nullptr, nullptr, 1024, 2048, 0.f, 2, SS, HS, SH, 0);

  // 6. out = LayerNorm(X + context)  — overwrites probs region (all reads done)
  ln_kernel<<<16384, 256, 0, stream>>>(X, Ctx, gamma, beta, out);
}

// Round 2
// 492.936 us; speedup vs baseline: 1.1241x; 1.1241x over previous
//
#include <hip/hip_runtime.h>
#include <stdint.h>
#include <stddef.h>

// ---------- types ----------
typedef _Float16 f16_t;
typedef _Float16 f16x8 __attribute__((ext_vector_type(8)));
typedef _Float16 f16x4 __attribute__((ext_vector_type(4)));
typedef float    f32x4 __attribute__((ext_vector_type(4)));

#define AS_G __attribute__((address_space(1)))
#define AS_L __attribute__((address_space(3)))

__device__ __forceinline__ void gload_lds16(const void* g, void* l) {
  // async global->LDS, 16B per lane; HW writes lds_base + lane*16
  __builtin_amdgcn_global_load_lds((const AS_G uint32_t*)g, (AS_L uint32_t*)l, 16, 0, 0);
}

#define LN_EPS 1e-12f
#define MASK_NEG -60000.0f  // f16-representable stand-in for -1e9 (exp -> 0)

// ---------- cast fp32 -> f16 (vectorized x4) ----------
__global__ __launch_bounds__(256) void cast_f16_kernel(const float* __restrict__ in,
                                                       f16_t* __restrict__ out) {
  int i = blockIdx.x * 256 + threadIdx.x;
  float4 v = ((const float4*)in)[i];
  f16x4 o = {(f16_t)v.x, (f16_t)v.y, (f16_t)v.z, (f16_t)v.w};
  ((f16x4*)out)[i] = o;
}

// ---------- tiled transpose + cast: in [b][R][C] f32 -> out [b][C][R] f16 ----------
__global__ __launch_bounds__(256) void transpose_f16_kernel(const float* __restrict__ in,
                                                            f16_t* __restrict__ out,
                                                            int R, int C) {
  __shared__ float tile[32][33];
  int b = blockIdx.z;
  const float* inb = in + (size_t)b * R * C;
  f16_t* outb = out + (size_t)b * R * C;
  int tx = threadIdx.x, ty = threadIdx.y;  // 32 x 8
  int c0 = blockIdx.x * 32, r0 = blockIdx.y * 32;
#pragma unroll
  for (int i = 0; i < 32; i += 8)
    tile[ty + i][tx] = inb[(size_t)(r0 + ty + i) * C + (c0 + tx)];
  __syncthreads();
#pragma unroll
  for (int i = 0; i < 32; i += 8)
    outb[(size_t)(c0 + ty + i) * R + (r0 + tx)] = (f16_t)tile[tx][ty + i];
}

// ---------- 128x128 MFMA GEMM, C = A[MxK] * Bt[NxK]^T, f16 in, f16 out ----------
// BK=64, XOR-swizzled LDS (chunk c of row r stored at slot c^(r&7)) -> bank-conflict-free
// mode 0: + (col < nhalf ? biasq[col] : biask[col-nhalf])   (fused Q/K projection)
// mode 1: *scale, mask[col]==0 -> MASK_NEG                  (scores)
// mode 2: plain                                             (P @ V context)
__global__ __launch_bounds__(256) void gemm_bt_kernel(
    const f16_t* __restrict__ A, const f16_t* __restrict__ Bt, f16_t* __restrict__ C,
    const float* __restrict__ biasq, const float* __restrict__ biask,
    const int* __restrict__ mask,
    int lda, int ldb, int ldc, int K, float scale, int mode, int nhalf,
    size_t sA, size_t sB, size_t sC, size_t sMask) {
  __shared__ f16_t As[128 * 64];
  __shared__ f16_t Bs[128 * 64];

  const int tid = threadIdx.x;
  const int lane = tid & 63;
  const int wv = tid >> 6;          // wave 0..3
  const int m16 = lane & 15;
  const int quad = lane >> 4;
  const int wr = (wv >> 1) * 64;    // wave row offset in tile
  const int wc = (wv & 1) * 64;     // wave col offset in tile

  const f16_t* Ab = A + blockIdx.z * sA + (size_t)blockIdx.x * 128 * lda;
  const f16_t* Bb = Bt + blockIdx.z * sB + (size_t)blockIdx.y * 128 * ldb;

  // staging: each wave stages 32 rows of A and B per iter, 4 calls of 1KB each.
  // call j covers rows wv*32 + j*8 + (0..7); lane = row_local8*8 + slot;
  // content chunk = slot ^ (row&7)  (the XOR swizzle).
  const int lr8 = lane >> 3;            // 0..7
  const int ch8 = (lane & 7) ^ lr8;     // swizzled chunk this lane fetches
  const f16_t* gA[4]; const f16_t* gB[4];
  f16_t* lA[4]; f16_t* lB[4];
#pragma unroll
  for (int j = 0; j < 4; ++j) {
    int row = wv * 32 + j * 8 + lr8;
    gA[j] = Ab + (size_t)row * lda + ch8 * 8;
    gB[j] = Bb + (size_t)row * ldb + ch8 * 8;
    lA[j] = &As[(wv * 32 + j * 8) * 64];
    lB[j] = &Bs[(wv * 32 + j * 8) * 64];
  }

  // fragment-read offsets (elements): row r, chunk c -> r*64 + (c^(r&7))*8
  int aoff[4], boff[4], swz[2];
#pragma unroll
  for (int t = 0; t < 4; ++t) {
    aoff[t] = (wr + t * 16 + m16) * 64;
    boff[t] = (wc + t * 16 + m16) * 64;
  }
#pragma unroll
  for (int s = 0; s < 2; ++s)
    swz[s] = (((s << 2) | quad) ^ (m16 & 7)) * 8;

  f32x4 acc[4][4] = {};

  for (int k0 = 0; k0 < K; k0 += 64) {
#pragma unroll
    for (int j = 0; j < 4; ++j) {
      gload_lds16(gA[j] + k0, lA[j]);
      gload_lds16(gB[j] + k0, lB[j]);
    }
    __syncthreads();  // drains vmcnt, publishes LDS

#pragma unroll
    for (int s = 0; s < 2; ++s) {
      f16x8 af[4], bfr[4];
#pragma unroll
      for (int t = 0; t < 4; ++t) {
        af[t]  = *(const f16x8*)&As[aoff[t] + swz[s]];
        bfr[t] = *(const f16x8*)&Bs[boff[t] + swz[s]];
      }
#pragma unroll
      for (int rt = 0; rt < 4; ++rt)
#pragma unroll
        for (int ct = 0; ct < 4; ++ct)
          acc[rt][ct] = __builtin_amdgcn_mfma_f32_16x16x32_f16(af[rt], bfr[ct], acc[rt][ct], 0, 0, 0);
    }
    __syncthreads();
  }

  // epilogue; C/D layout: col = lane&15, row = quad*4 + reg  [m89-verified]
  f16_t* Cb = C + blockIdx.z * sC;
  const int row0 = blockIdx.x * 128 + wr + quad * 4;
  const int col0 = blockIdx.y * 128 + wc + m16;
  if (mode == 0) {
#pragma unroll
    for (int ct = 0; ct < 4; ++ct) {
      int col = col0 + ct * 16;
      float bv = (col < nhalf) ? biasq[col] : biask[col - nhalf];
#pragma unroll
      for (int rt = 0; rt < 4; ++rt)
#pragma unroll
        for (int r = 0; r < 4; ++r)
          Cb[(size_t)(row0 + rt * 16 + r) * ldc + col] = (f16_t)(acc[rt][ct][r] + bv);
    }
  } else if (mode == 1) {
    const int* mp = mask + blockIdx.z * sMask;
#pragma unroll
    for (int ct = 0; ct < 4; ++ct) {
      int col = col0 + ct * 16;
      bool keep = (mp[col] != 0);
#pragma unroll
      for (int rt = 0; rt < 4; ++rt)
#pragma unroll
        for (int r = 0; r < 4; ++r) {
          float v = keep ? acc[rt][ct][r] * scale : MASK_NEG;
          Cb[(size_t)(row0 + rt * 16 + r) * ldc + col] = (f16_t)v;
        }
    }
  } else {
#pragma unroll
    for (int ct = 0; ct < 4; ++ct) {
      int col = col0 + ct * 16;
#pragma unroll
      for (int rt = 0; rt < 4; ++rt)
#pragma unroll
        for (int r = 0; r < 4; ++r)
          Cb[(size_t)(row0 + rt * 16 + r) * ldc + col] = (f16_t)acc[rt][ct][r];
    }
  }
}

// ---------- row softmax in place: probs [16384][2048] f16 ----------
__global__ __launch_bounds__(256) void softmax_kernel(f16_t* probs) {
  __shared__ float redm[4], reds[4];
  const int tid = threadIdx.x;
  f16_t* p = probs + (size_t)blockIdx.x * 2048;
  f16x8 v8 = ((const f16x8*)p)[tid];
  float v[8];
#pragma unroll
  for (int j = 0; j < 8; ++j) v[j] = (float)v8[j];
  float mx = v[0];
#pragma unroll
  for (int j = 1; j < 8; ++j) mx = fmaxf(mx, v[j]);
#pragma unroll
  for (int off = 32; off > 0; off >>= 1) mx = fmaxf(mx, __shfl_xor(mx, off, 64));
  if ((tid & 63) == 0) redm[tid >> 6] = mx;
  __syncthreads();
  mx = fmaxf(fmaxf(redm[0], redm[1]), fmaxf(redm[2], redm[3]));
  float e[8], s = 0.f;
#pragma unroll
  for (int j = 0; j < 8; ++j) { e[j] = __expf(v[j] - mx); s += e[j]; }
#pragma unroll
  for (int off = 32; off > 0; off >>= 1) s += __shfl_xor(s, off, 64);
  if ((tid & 63) == 0) reds[tid >> 6] = s;
  __syncthreads();
  s = reds[0] + reds[1] + reds[2] + reds[3];
  float inv = 1.0f / s;
  f16x8 o;
#pragma unroll
  for (int j = 0; j < 8; ++j) o[j] = (f16_t)(e[j] * inv);
  ((f16x8*)p)[tid] = o;
}

// ---------- residual + LayerNorm: out[row] = LN(X[row] + Ctx[row]) ----------
__global__ __launch_bounds__(256) void ln_kernel(const float* __restrict__ X,
                                                 const f16_t* __restrict__ Ctx,
                                                 const float* __restrict__ gamma,
                                                 const float* __restrict__ beta,
                                                 float* __restrict__ out) {
  __shared__ float r1[4], r2[4];
  const int tid = threadIdx.x;
  const size_t base = (size_t)blockIdx.x * 1024;
  float4 xv = ((const float4*)(X + base))[tid];
  f16x4 cv = ((const f16x4*)(Ctx + base))[tid];
  float v0 = xv.x + (float)cv[0];
  float v1 = xv.y + (float)cv[1];
  float v2 = xv.z + (float)cv[2];
  float v3 = xv.w + (float)cv[3];
  float s1 = v0 + v1 + v2 + v3;
  float s2 = v0 * v0 + v1 * v1 + v2 * v2 + v3 * v3;
#pragma unroll
  for (int off = 32; off > 0; off >>= 1) {
    s1 += __shfl_xor(s1, off, 64);
    s2 += __shfl_xor(s2, off, 64);
  }
  if ((tid & 63) == 0) { r1[tid >> 6] = s1; r2[tid >> 6] = s2; }
  __syncthreads();
  s1 = r1[0] + r1[1] + r1[2] + r1[3];
  s2 = r2[0] + r2[1] + r2[2] + r2[3];
  float mu = s1 * (1.0f / 1024.0f);
  float var = s2 * (1.0f / 1024.0f) - mu * mu;
  float rs = rsqrtf(fmaxf(var, 0.0f) + LN_EPS);
  float4 gv = ((const float4*)gamma)[tid];
  float4 bv = ((const float4*)beta)[tid];
  float4 o;
  o.x = (v0 - mu) * rs * gv.x + bv.x;
  o.y = (v1 - mu) * rs * gv.y + bv.y;
  o.z = (v2 - mu) * rs * gv.z + bv.z;
  o.w = (v3 - mu) * rs * gv.w + bv.w;
  ((float4*)(out + base))[tid] = o;
}

// ---------- launch ----------
extern "C" void kernel_launch(void* const* d_in, const int* in_sizes, int n_in,
                              void* d_out, int out_size, void* d_ws, size_t ws_size,
                              hipStream_t stream) {
  const float* X     = (const float*)d_in[0];  // [8,2048,1024]
  const int*   masks = (const int*)d_in[1];    // [8,2048]
  const float* Wq    = (const float*)d_in[2];  // [1024,1024]
  const float* bq    = (const float*)d_in[3];
  const float* Wk    = (const float*)d_in[4];
  const float* bk    = (const float*)d_in[5];
  const float* gamma = (const float*)d_in[6];
  const float* beta  = (const float*)d_in[7];
  float* out = (float*)d_out;

  if (ws_size < 138412032u) return;  // need 132 MiB
  char* ws = (char*)d_ws;
  f16_t* Xb    = (f16_t*)(ws + 0);          // [16384][1024] f16 (also Ctx later)
  f16_t* Xt    = (f16_t*)(ws + 33554432);   // [8][1024][2048] f16  (X^T per batch)
  f16_t* WqkT  = (f16_t*)(ws + 67108864);   // [2048][1024] f16 ([Wq^T ; Wk^T])
  f16_t* QKb   = (f16_t*)(ws + 71303168);   // [16384][2048] f16 (Q | K concat cols)
  f16_t* Ctx = Xb;
  f16_t* probs = (f16_t*)d_out;             // [8][2048][2048] f16 == 64 MiB == d_out

  const size_t SH = 2048u * 1024u;          // per-batch stride of [S,H]
  const size_t SS = 2048u * 2048u;          // per-batch stride of [S,S]
  const size_t HS = 1024u * 2048u;          // per-batch stride of [H,S]
  const size_t S2 = 2048u * 2048u;          // per-batch stride of QKb rows

  // 1. casts / transposes
  cast_f16_kernel<<<16384, 256, 0, stream>>>(X, Xb);
  transpose_f16_kernel<<<dim3(32, 64, 8), dim3(32, 8), 0, stream>>>(X, Xt, 2048, 1024);
  transpose_f16_kernel<<<dim3(32, 32, 1), dim3(32, 8), 0, stream>>>(Wq, WqkT, 1024, 1024);
  transpose_f16_kernel<<<dim3(32, 32, 1), dim3(32, 8), 0, stream>>>(Wk, WqkT + 1024 * 1024, 1024, 1024);

  // 2. fused [Q|K] = X * [Wq|Wk] + [bq|bk]   (M=16384, N=2048, K=1024)
  gemm_bt_kernel<<<dim3(128, 16, 1), 256, 0, stream>>>(
      Xb, WqkT, QKb, bq, bk, nullptr,
      1024, 1024, 2048, 1024, 0.f, 0, 1024, 0, 0, 0, 0);

  // 3. scores = Q K^T / 32, masked   (per batch: M=2048, N=2048, K=1024)
  gemm_bt_kernel<<<dim3(16, 16, 8), 256, 0, stream>>>(
      QKb, QKb + 1024, probs, nullptr, nullptr, masks,
      2048, 2048, 2048, 1024, 0.03125f, 1, 0, S2, S2, SS, 2048);

  // 4. softmax rows in place
  softmax_kernel<<<16384, 256, 0, stream>>>(probs);

  // 5. context = P @ X   (per batch: M=2048, N=1024, K=2048; Bt = X^T)
  gemm_bt_kernel<<<dim3(16, 8, 8), 256, 0, stream>>>(
      probs, Xt, Ctx, nullptr, nullptr, nullptr,
      2048, 2048, 1024, 2048, 0.f, 2, 0, SS, HS, SH, 0);

  // 6. out = LayerNorm(X + context)  — overwrites probs region (all reads done)
  ln_kernel<<<16384, 256, 0, stream>>>(X, Ctx, gamma, beta, out);
}